// Round 1
// baseline (609.628 us; speedup 1.0000x reference)
//
#include <hip/hip_runtime.h>

#define MT 45012
#define NTOT 11253
#define BB 4

typedef __attribute__((ext_vector_type(8))) __bf16 bf16x8;
typedef __attribute__((ext_vector_type(4))) float f32x4;

__device__ __forceinline__ unsigned short f2bf(float f) {
  unsigned u = __float_as_uint(f);
  u += 0x7FFFu + ((u >> 16) & 1u);
  return (unsigned short)(u >> 16);
}

// ---------------- weight prep ----------------
__global__ __launch_bounds__(256) void wt_transpose(const float* __restrict__ W,
                                                    unsigned short* __restrict__ Wt,
                                                    int K, int N) {
  int i = blockIdx.x * 256 + threadIdx.x;
  if (i >= K * N) return;
  int n = i / K, k = i % K;
  Wt[i] = f2bf(W[(size_t)k * N + n]);
}

__global__ __launch_bounds__(256) void cvec_kernel(const float* __restrict__ Woff,
                                                   const float* __restrict__ Wattn,
                                                   float* __restrict__ c_off,
                                                   float* __restrict__ c_attn) {
  int i = blockIdx.x * 256 + threadIdx.x;
  if (i < 256) c_off[i] = Woff[256 * 256 + i];
  else if (i < 384) c_attn[i - 256] = Wattn[256 * 128 + (i - 256)];
}

// ---------------- activation convert: src_bf16, qa = bf16(src+pos) ----------------
__global__ __launch_bounds__(256) void cvt_kernel(const float4* __restrict__ src4,
                                                  const float4* __restrict__ pos4,
                                                  ushort4* __restrict__ sb,
                                                  ushort4* __restrict__ qb) {
  int i = blockIdx.x * 256 + threadIdx.x;
  if (i >= MT * 64) return;
  float4 s = src4[i], p = pos4[i];
  sb[i] = make_ushort4(f2bf(s.x), f2bf(s.y), f2bf(s.z), f2bf(s.w));
  qb[i] = make_ushort4(f2bf(s.x + p.x), f2bf(s.y + p.y), f2bf(s.z + p.z), f2bf(s.w + p.w));
}

// ---------------- per (b,level) corr-softmax stats ----------------
__global__ __launch_bounds__(256) void stats_kernel(const float* __restrict__ c0,
                                                    const float* __restrict__ c1,
                                                    const float* __restrict__ c2,
                                                    const float* __restrict__ c3,
                                                    const float* __restrict__ vr,
                                                    float* __restrict__ stats) {
  const int LS[4] = {92, 46, 23, 12};
  const int LHW[4] = {8464, 2116, 529, 144};
  int b = blockIdx.x >> 2, l = blockIdx.x & 3;
  const float* cp = (l == 0) ? c0 : (l == 1) ? c1 : (l == 2) ? c2 : c3;
  int S = LS[l], HW = LHW[l];
  float vrx = vr[(b * 4 + l) * 2 + 0], vry = vr[(b * 4 + l) * 2 + 1];
  int tid = threadIdx.x;
  __shared__ float red[4];

  float mx = -INFINITY;
  for (int i = tid; i < HW; i += 256) {
    float c = cp[(size_t)b * HW + i];
    if (c >= 0.5f) mx = fmaxf(mx, c);
  }
  for (int o = 32; o; o >>= 1) mx = fmaxf(mx, __shfl_xor(mx, o));
  if ((tid & 63) == 0) red[tid >> 6] = mx;
  __syncthreads();
  mx = fmaxf(fmaxf(red[0], red[1]), fmaxf(red[2], red[3]));
  float mx_eff = isinf(mx) ? 0.f : mx;
  __syncthreads();

  float den = 0.f, cx = 0.f, cy = 0.f;
  float invW = 1.f / (vrx * (float)S), invH = 1.f / (vry * (float)S);
  for (int i = tid; i < HW; i += 256) {
    float c = cp[(size_t)b * HW + i];
    if (c >= 0.5f) {
      float e = expf(c - mx_eff);
      int x = i % S, y = i / S;
      den += e;
      cx += e * ((float)x + 0.5f) * invW;
      cy += e * ((float)y + 0.5f) * invH;
    }
  }
  float vals[3] = {den, cx, cy};
  for (int j = 0; j < 3; ++j) {
    float v = vals[j];
    for (int o = 32; o; o >>= 1) v += __shfl_xor(v, o);
    if ((tid & 63) == 0) red[tid >> 6] = v;
    __syncthreads();
    v = red[0] + red[1] + red[2] + red[3];
    vals[j] = v;
    __syncthreads();
  }
  if (tid == 0) {
    float* s = stats + (size_t)(b * 4 + l) * 4;
    s[0] = mx_eff; s[1] = vals[0]; s[2] = vals[1]; s[3] = vals[2];
  }
}

// ---------------- reference points + corr_all ----------------
__global__ __launch_bounds__(256) void refpt_kernel(const float* __restrict__ c0,
                                                    const float* __restrict__ c1,
                                                    const float* __restrict__ c2,
                                                    const float* __restrict__ c3,
                                                    const float* __restrict__ vr,
                                                    const float* __restrict__ stats,
                                                    float* __restrict__ refpt,
                                                    float* __restrict__ corr_all) {
  int i = blockIdx.x * 256 + threadIdx.x;
  if (i >= MT) return;
  int b = i / NTOT, n = i % NTOT;
  int l = (n < 8464) ? 0 : (n < 10580) ? 1 : (n < 11109) ? 2 : 3;
  const int LS[4] = {92, 46, 23, 12};
  const int LSTART[4] = {0, 8464, 10580, 11109};
  const int LHW[4] = {8464, 2116, 529, 144};
  int S = LS[l], start = LSTART[l], HW = LHW[l];
  int local = n - start;
  int x = local % S, y = local / S;
  float vrx = vr[(b * 4 + l) * 2 + 0], vry = vr[(b * 4 + l) * 2 + 1];
  float rx = ((float)x + 0.5f) / (vrx * (float)S);
  float ry = ((float)y + 0.5f) / (vry * (float)S);
  const float* cp = (l == 0) ? c0 : (l == 1) ? c1 : (l == 2) ? c2 : c3;
  float c = cp[(size_t)b * HW + local];
  const float* st = stats + (size_t)(b * 4 + l) * 4;
  float mx = st[0], den = st[1], cxs = st[2], cys = st[3];
  float sm = 0.f, cenx = 0.f, ceny = 0.f;
  if (den > 0.f) {
    if (c >= 0.5f) sm = expf(c - mx) / fmaxf(den, 1e-30f);
    cenx = cxs / den; ceny = cys / den;
  }
  float dx = fminf(fmaxf(cenx - rx, -0.5f), 0.5f) * sm;
  float dy = fminf(fmaxf(ceny - ry, -0.5f), 0.5f) * sm;
  refpt[2 * i] = rx + dx;
  refpt[2 * i + 1] = ry + dy;
  corr_all[i] = c;
}

// ---------------- bf16 MFMA GEMM: C[M,N] = A[M,K] * Bt[N,K]^T ----------------
// EPI: 0 = f32 out + bias
//      1 = f32 out + bias + corr[row]*cvec[col]
//      2 = f32 out + bias + resid[row*N+col]
//      3 = bf16 out = bf16(relu(acc + bias))
template <int EPI>
__global__ __launch_bounds__(256) void gemm_bf16(const unsigned short* __restrict__ A,
                                                 const unsigned short* __restrict__ Bt,
                                                 const float* __restrict__ bias,
                                                 const float* __restrict__ cvec,
                                                 const float* __restrict__ corr,
                                                 const float* __restrict__ resid,
                                                 void* __restrict__ out,
                                                 int K, int N) {
  const int tid = threadIdx.x;
  const int wid = tid >> 6, lane = tid & 63;
  const int row0 = blockIdx.x * 64;
  const int col0 = blockIdx.y * 128;
  const int wm = wid >> 1, wn = wid & 1;
  const int l15 = lane & 15, lk = (lane >> 4) * 8;

  __shared__ __align__(16) unsigned short Als[64 * 40];
  __shared__ __align__(16) unsigned short Bls[128 * 40];

  f32x4 acc[2][4];
  const f32x4 zero = {0.f, 0.f, 0.f, 0.f};
#pragma unroll
  for (int a = 0; a < 2; ++a)
#pragma unroll
    for (int c = 0; c < 4; ++c) acc[a][c] = zero;

  const int srow = tid >> 2, sseg = tid & 3;
  for (int k0 = 0; k0 < K; k0 += 32) {
    __syncthreads();
    {
      int grow = row0 + srow;
      uint4 v = make_uint4(0, 0, 0, 0);
      if (grow < MT) v = *(const uint4*)(A + (size_t)grow * K + k0 + sseg * 8);
      *(uint4*)(&Als[srow * 40 + sseg * 8]) = v;
    }
#pragma unroll
    for (int it = 0; it < 2; ++it) {
      int r = srow + it * 64;
      uint4 v = *(const uint4*)(Bt + (size_t)(col0 + r) * K + k0 + sseg * 8);
      *(uint4*)(&Bls[r * 40 + sseg * 8]) = v;
    }
    __syncthreads();
    bf16x8 av[2], bv[4];
#pragma unroll
    for (int fm = 0; fm < 2; ++fm)
      av[fm] = *(const bf16x8*)(&Als[(wm * 32 + fm * 16 + l15) * 40 + lk]);
#pragma unroll
    for (int fn = 0; fn < 4; ++fn)
      bv[fn] = *(const bf16x8*)(&Bls[(wn * 64 + fn * 16 + l15) * 40 + lk]);
#pragma unroll
    for (int fm = 0; fm < 2; ++fm)
#pragma unroll
      for (int fn = 0; fn < 4; ++fn)
        acc[fm][fn] = __builtin_amdgcn_mfma_f32_16x16x32_bf16(av[fm], bv[fn], acc[fm][fn], 0, 0, 0);
  }

#pragma unroll
  for (int fm = 0; fm < 2; ++fm) {
#pragma unroll
    for (int fn = 0; fn < 4; ++fn) {
      int gcol = col0 + wn * 64 + fn * 16 + l15;
      float bcol = bias[gcol];
#pragma unroll
      for (int r = 0; r < 4; ++r) {
        int grow = row0 + wm * 32 + fm * 16 + (lane >> 4) * 4 + r;
        if (grow < MT) {
          float v = acc[fm][fn][r] + bcol;
          if constexpr (EPI == 1) v += corr[grow] * cvec[gcol];
          if constexpr (EPI == 2) v += resid[(size_t)grow * N + gcol];
          if constexpr (EPI == 3) {
            ((unsigned short*)out)[(size_t)grow * N + gcol] = f2bf(fmaxf(v, 0.f));
          } else {
            ((float*)out)[(size_t)grow * N + gcol] = v;
          }
        }
      }
    }
  }
}

// ---------------- softmax over groups of 16 (attn weights) ----------------
__global__ __launch_bounds__(256) void softmax16(float* __restrict__ a) {
  int idx = blockIdx.x * 256 + threadIdx.x;
  if (idx >= MT * 8) return;
  float* p = a + (size_t)idx * 16;
  float4 v0 = ((float4*)p)[0], v1 = ((float4*)p)[1], v2 = ((float4*)p)[2], v3 = ((float4*)p)[3];
  float m = fmaxf(fmaxf(fmaxf(v0.x, v0.y), fmaxf(v0.z, v0.w)),
                  fmaxf(fmaxf(fmaxf(v1.x, v1.y), fmaxf(v1.z, v1.w)),
                        fmaxf(fmaxf(fmaxf(v2.x, v2.y), fmaxf(v2.z, v2.w)),
                              fmaxf(fmaxf(v3.x, v3.y), fmaxf(v3.z, v3.w)))));
  v0.x = expf(v0.x - m); v0.y = expf(v0.y - m); v0.z = expf(v0.z - m); v0.w = expf(v0.w - m);
  v1.x = expf(v1.x - m); v1.y = expf(v1.y - m); v1.z = expf(v1.z - m); v1.w = expf(v1.w - m);
  v2.x = expf(v2.x - m); v2.y = expf(v2.y - m); v2.z = expf(v2.z - m); v2.w = expf(v2.w - m);
  v3.x = expf(v3.x - m); v3.y = expf(v3.y - m); v3.z = expf(v3.z - m); v3.w = expf(v3.w - m);
  float s = v0.x + v0.y + v0.z + v0.w + v1.x + v1.y + v1.z + v1.w +
            v2.x + v2.y + v2.z + v2.w + v3.x + v3.y + v3.z + v3.w;
  float inv = 1.f / s;
  v0.x *= inv; v0.y *= inv; v0.z *= inv; v0.w *= inv;
  v1.x *= inv; v1.y *= inv; v1.z *= inv; v1.w *= inv;
  v2.x *= inv; v2.y *= inv; v2.z *= inv; v2.w *= inv;
  v3.x *= inv; v3.y *= inv; v3.z *= inv; v3.w *= inv;
  ((float4*)p)[0] = v0; ((float4*)p)[1] = v1; ((float4*)p)[2] = v2; ((float4*)p)[3] = v3;
}

// ---------------- deformable sampling ----------------
__global__ __launch_bounds__(256) void sampler_kernel(const float* __restrict__ value,
                                                      const float* __restrict__ offs,
                                                      const float* __restrict__ attw,
                                                      const float* __restrict__ refpt,
                                                      const float* __restrict__ vr,
                                                      unsigned short* __restrict__ outs) {
  const int LS[4] = {92, 46, 23, 12};
  const int LSTART[4] = {0, 8464, 10580, 11109};
  int r = blockIdx.x;
  int tid = threadIdx.x;
  int h = tid >> 5;
  int b = r / NTOT;
  __shared__ float s_off[256];
  __shared__ float s_att[128];
  __shared__ float s_ref[2];
  s_off[tid] = offs[(size_t)r * 256 + tid];
  if (tid < 128) s_att[tid] = attw[(size_t)r * 128 + tid];
  if (tid < 2) s_ref[tid] = refpt[2 * r + tid];
  __syncthreads();

  float acc = 0.f;
  const float* vbase = value + (size_t)b * NTOT * 256 + tid;
#pragma unroll
  for (int l = 0; l < 4; ++l) {
    const int S = LS[l];
    const float fS = (float)S;
    const float inv = 1.f / fS;
    float vrx = vr[(b * 4 + l) * 2 + 0], vry = vr[(b * 4 + l) * 2 + 1];
    float px = s_ref[0] * vrx, py = s_ref[1] * vry;
    const float* vl = vbase + (size_t)LSTART[l] * 256;
#pragma unroll
    for (int p = 0; p < 4; ++p) {
      int oi = ((h * 4 + l) * 4 + p) * 2;
      float lx = px + s_off[oi] * inv;
      float ly = py + s_off[oi + 1] * inv;
      float w = s_att[h * 16 + l * 4 + p];
      float xf = lx * fS - 0.5f, yf = ly * fS - 0.5f;
      float x0f = floorf(xf), y0f = floorf(yf);
      float wx = xf - x0f, wy = yf - y0f;
      int x0 = (int)x0f, y0 = (int)y0f;
      int x1 = x0 + 1, y1 = y0 + 1;
      bool bx0 = (unsigned)x0 < (unsigned)S, bx1 = (unsigned)x1 < (unsigned)S;
      bool by0 = (unsigned)y0 < (unsigned)S, by1 = (unsigned)y1 < (unsigned)S;
      float v00 = (bx0 && by0) ? vl[(size_t)(y0 * S + x0) * 256] : 0.f;
      float v01 = (bx1 && by0) ? vl[(size_t)(y0 * S + x1) * 256] : 0.f;
      float v10 = (bx0 && by1) ? vl[(size_t)(y1 * S + x0) * 256] : 0.f;
      float v11 = (bx1 && by1) ? vl[(size_t)(y1 * S + x1) * 256] : 0.f;
      float top = v00 + (v01 - v00) * wx;
      float bot = v10 + (v11 - v10) * wx;
      acc += w * (top + (bot - top) * wy);
    }
  }
  outs[(size_t)r * 256 + tid] = f2bf(acc);
}

// ---------------- layernorm (256 cols, 1 wave per row) ----------------
__global__ __launch_bounds__(256) void ln_kernel(const float* __restrict__ in,
                                                 const float* __restrict__ g,
                                                 const float* __restrict__ b,
                                                 float* __restrict__ outf,
                                                 ushort4* __restrict__ outbf) {
  int row = blockIdx.x * 4 + (threadIdx.x >> 6);
  int lane = threadIdx.x & 63;
  if (row >= MT) return;
  const float4* p = (const float4*)(in + (size_t)row * 256);
  float4 v = p[lane];
  float s = v.x + v.y + v.z + v.w;
  for (int o = 32; o; o >>= 1) s += __shfl_xor(s, o);
  float mean = s * (1.f / 256.f);
  float dx = v.x - mean, dy = v.y - mean, dz = v.z - mean, dw = v.w - mean;
  float q = dx * dx + dy * dy + dz * dz + dw * dw;
  for (int o = 32; o; o >>= 1) q += __shfl_xor(q, o);
  float rstd = rsqrtf(q * (1.f / 256.f) + 1e-5f);
  float4 gv = ((const float4*)g)[lane];
  float4 bv = ((const float4*)b)[lane];
  float4 o;
  o.x = dx * rstd * gv.x + bv.x;
  o.y = dy * rstd * gv.y + bv.y;
  o.z = dz * rstd * gv.z + bv.z;
  o.w = dw * rstd * gv.w + bv.w;
  ((float4*)(outf + (size_t)row * 256))[lane] = o;
  if (outbf) outbf[(size_t)row * 64 + lane] = make_ushort4(f2bf(o.x), f2bf(o.y), f2bf(o.z), f2bf(o.w));
}

// ---------------- launch ----------------
extern "C" void kernel_launch(void* const* d_in, const int* in_sizes, int n_in,
                              void* d_out, int out_size, void* d_ws, size_t ws_size,
                              hipStream_t stream) {
  (void)in_sizes; (void)n_in; (void)out_size; (void)ws_size;
  const float* src = (const float*)d_in[0];
  const float* pos = (const float*)d_in[1];
  const float* c0 = (const float*)d_in[2];
  const float* c1 = (const float*)d_in[3];
  const float* c2 = (const float*)d_in[4];
  const float* c3 = (const float*)d_in[5];
  const float* vr = (const float*)d_in[6];
  const float* W_off = (const float*)d_in[8];
  const float* b_off = (const float*)d_in[9];
  const float* W_attn = (const float*)d_in[10];
  const float* b_attn = (const float*)d_in[11];
  const float* W_val = (const float*)d_in[12];
  const float* b_val = (const float*)d_in[13];
  const float* W_out = (const float*)d_in[14];
  const float* b_out = (const float*)d_in[15];
  const float* ln1g = (const float*)d_in[16];
  const float* ln1b = (const float*)d_in[17];
  const float* W1 = (const float*)d_in[18];
  const float* b1 = (const float*)d_in[19];
  const float* W2 = (const float*)d_in[20];
  const float* b2 = (const float*)d_in[21];
  const float* ln2g = (const float*)d_in[22];
  const float* ln2b = (const float*)d_in[23];

  char* ws = (char*)d_ws;
  // slot S1 (46MB): value -> t -> x -> u  (in-place chains are per-element safe)
  float* value = (float*)(ws + 0);
  float* tbuf = value;
  float* xbuf = value;
  float* ubuf = value;
  // slot S2 (46MB): offs; later x_bf16 in front half
  float* offs = (float*)(ws + 46092288);
  unsigned short* x_bf16 = (unsigned short*)(ws + 46092288);
  // slot S4 (23MB): src_bf16 -> out_s
  unsigned short* src_bf16 = (unsigned short*)(ws + 92184576);
  unsigned short* out_s = src_bf16;
  // region C (92MB): qa (front 23MB) + logits (next 23MB); later h spans all
  unsigned short* qa = (unsigned short*)(ws + 115230720);
  float* logits = (float*)(ws + 138276864);
  unsigned short* hbuf = (unsigned short*)(ws + 115230720);
  // small region
  unsigned short* Wt_val = (unsigned short*)(ws + 207415296);
  unsigned short* Wt_off = (unsigned short*)(ws + 207546368);
  unsigned short* Wt_attn = (unsigned short*)(ws + 207677440);
  unsigned short* Wt_out = (unsigned short*)(ws + 207742976);
  unsigned short* Wt1 = (unsigned short*)(ws + 207874048);
  unsigned short* Wt2 = (unsigned short*)(ws + 208398336);
  float* c_off = (float*)(ws + 208922624);
  float* c_attn = (float*)(ws + 208923648);
  float* refpt = (float*)(ws + 208924160);
  float* corr_all = (float*)(ws + 209284256);
  float* stats = (float*)(ws + 209464304);

  // weight prep
  wt_transpose<<<256, 256, 0, stream>>>(W_val, Wt_val, 256, 256);
  wt_transpose<<<256, 256, 0, stream>>>(W_off, Wt_off, 256, 256);
  wt_transpose<<<128, 256, 0, stream>>>(W_attn, Wt_attn, 256, 128);
  wt_transpose<<<256, 256, 0, stream>>>(W_out, Wt_out, 256, 256);
  wt_transpose<<<1024, 256, 0, stream>>>(W1, Wt1, 256, 1024);
  wt_transpose<<<1024, 256, 0, stream>>>(W2, Wt2, 1024, 256);
  cvec_kernel<<<2, 256, 0, stream>>>(W_off, W_attn, c_off, c_attn);

  // activations
  cvt_kernel<<<11253, 256, 0, stream>>>((const float4*)src, (const float4*)pos,
                                        (ushort4*)src_bf16, (ushort4*)qa);
  // reference points
  stats_kernel<<<16, 256, 0, stream>>>(c0, c1, c2, c3, vr, stats);
  refpt_kernel<<<176, 256, 0, stream>>>(c0, c1, c2, c3, vr, stats, refpt, corr_all);

  dim3 blk(256);
  // value = src @ W_val + b_val
  gemm_bf16<0><<<dim3(704, 2), blk, 0, stream>>>(src_bf16, Wt_val, b_val, nullptr, nullptr, nullptr, value, 256, 256);
  // offsets = qa @ W_off + corr*c_off + b_off
  gemm_bf16<1><<<dim3(704, 2), blk, 0, stream>>>(qa, Wt_off, b_off, c_off, corr_all, nullptr, offs, 256, 256);
  // attn logits
  gemm_bf16<1><<<dim3(704, 1), blk, 0, stream>>>(qa, Wt_attn, b_attn, c_attn, corr_all, nullptr, logits, 256, 128);
  softmax16<<<1407, 256, 0, stream>>>(logits);
  // deformable sampling -> out_s (bf16)
  sampler_kernel<<<MT, 256, 0, stream>>>(value, offs, logits, refpt, vr, out_s);
  // out proj + residual: t = out_s @ W_out + b_out + src
  gemm_bf16<2><<<dim3(704, 2), blk, 0, stream>>>(out_s, Wt_out, b_out, nullptr, nullptr, src, tbuf, 256, 256);
  // LN1: x (f32, in-place) + x_bf16
  ln_kernel<<<11253, 256, 0, stream>>>(tbuf, ln1g, ln1b, xbuf, (ushort4*)x_bf16);
  // FFN1: h = bf16(relu(x @ W1 + b1))
  gemm_bf16<3><<<dim3(704, 8), blk, 0, stream>>>(x_bf16, Wt1, b1, nullptr, nullptr, nullptr, hbuf, 256, 1024);
  // FFN2: u = h @ W2 + b2 + x  (in-place into S1)
  gemm_bf16<2><<<dim3(704, 2), blk, 0, stream>>>(hbuf, Wt2, b2, nullptr, nullptr, xbuf, ubuf, 1024, 256);
  // LN2 -> d_out
  ln_kernel<<<11253, 256, 0, stream>>>(ubuf, ln2g, ln2b, (float*)d_out, nullptr);
}

// Round 3
// 390.528 us; speedup vs baseline: 1.5610x; 1.5610x over previous
//
#include <hip/hip_runtime.h>

#define MT 45012
#define NTOT 11253
#define BB 4

typedef __attribute__((ext_vector_type(8))) __bf16 bf16x8;
typedef __attribute__((ext_vector_type(4))) float f32x4;

__device__ __forceinline__ unsigned short f2bf(float f) {
  unsigned u = __float_as_uint(f);
  u += 0x7FFFu + ((u >> 16) & 1u);
  return (unsigned short)(u >> 16);
}

// ---------------- weight prep ----------------
__global__ __launch_bounds__(256) void wt_transpose(const float* __restrict__ W,
                                                    unsigned short* __restrict__ Wt,
                                                    int K, int N) {
  int i = blockIdx.x * 256 + threadIdx.x;
  if (i >= K * N) return;
  int n = i / K, k = i % K;
  Wt[i] = f2bf(W[(size_t)k * N + n]);
}

__global__ __launch_bounds__(256) void cvec_kernel(const float* __restrict__ Woff,
                                                   const float* __restrict__ Wattn,
                                                   float* __restrict__ c_off,
                                                   float* __restrict__ c_attn) {
  int i = blockIdx.x * 256 + threadIdx.x;
  if (i < 256) c_off[i] = Woff[256 * 256 + i];
  else if (i < 384) c_attn[i - 256] = Wattn[256 * 128 + (i - 256)];
}

// ---------------- activation convert: src_bf16, qa = bf16(src+pos) ----------------
__global__ __launch_bounds__(256) void cvt_kernel(const float4* __restrict__ src4,
                                                  const float4* __restrict__ pos4,
                                                  ushort4* __restrict__ sb,
                                                  ushort4* __restrict__ qb) {
  int i = blockIdx.x * 256 + threadIdx.x;
  if (i >= MT * 64) return;
  float4 s = src4[i], p = pos4[i];
  sb[i] = make_ushort4(f2bf(s.x), f2bf(s.y), f2bf(s.z), f2bf(s.w));
  qb[i] = make_ushort4(f2bf(s.x + p.x), f2bf(s.y + p.y), f2bf(s.z + p.z), f2bf(s.w + p.w));
}

// ---------------- per (b,level) corr-softmax stats ----------------
__global__ __launch_bounds__(256) void stats_kernel(const float* __restrict__ c0,
                                                    const float* __restrict__ c1,
                                                    const float* __restrict__ c2,
                                                    const float* __restrict__ c3,
                                                    const float* __restrict__ vr,
                                                    float* __restrict__ stats) {
  const int LS[4] = {92, 46, 23, 12};
  const int LHW[4] = {8464, 2116, 529, 144};
  int b = blockIdx.x >> 2, l = blockIdx.x & 3;
  const float* cp = (l == 0) ? c0 : (l == 1) ? c1 : (l == 2) ? c2 : c3;
  int S = LS[l], HW = LHW[l];
  float vrx = vr[(b * 4 + l) * 2 + 0], vry = vr[(b * 4 + l) * 2 + 1];
  int tid = threadIdx.x;
  __shared__ float red[4];

  float mx = -INFINITY;
  for (int i = tid; i < HW; i += 256) {
    float c = cp[(size_t)b * HW + i];
    if (c >= 0.5f) mx = fmaxf(mx, c);
  }
  for (int o = 32; o; o >>= 1) mx = fmaxf(mx, __shfl_xor(mx, o));
  if ((tid & 63) == 0) red[tid >> 6] = mx;
  __syncthreads();
  mx = fmaxf(fmaxf(red[0], red[1]), fmaxf(red[2], red[3]));
  float mx_eff = isinf(mx) ? 0.f : mx;
  __syncthreads();

  float den = 0.f, cx = 0.f, cy = 0.f;
  float invW = 1.f / (vrx * (float)S), invH = 1.f / (vry * (float)S);
  for (int i = tid; i < HW; i += 256) {
    float c = cp[(size_t)b * HW + i];
    if (c >= 0.5f) {
      float e = expf(c - mx_eff);
      int x = i % S, y = i / S;
      den += e;
      cx += e * ((float)x + 0.5f) * invW;
      cy += e * ((float)y + 0.5f) * invH;
    }
  }
  float vals[3] = {den, cx, cy};
  for (int j = 0; j < 3; ++j) {
    float v = vals[j];
    for (int o = 32; o; o >>= 1) v += __shfl_xor(v, o);
    if ((tid & 63) == 0) red[tid >> 6] = v;
    __syncthreads();
    v = red[0] + red[1] + red[2] + red[3];
    vals[j] = v;
    __syncthreads();
  }
  if (tid == 0) {
    float* s = stats + (size_t)(b * 4 + l) * 4;
    s[0] = mx_eff; s[1] = vals[0]; s[2] = vals[1]; s[3] = vals[2];
  }
}

// ---------------- reference points + corr_all ----------------
__global__ __launch_bounds__(256) void refpt_kernel(const float* __restrict__ c0,
                                                    const float* __restrict__ c1,
                                                    const float* __restrict__ c2,
                                                    const float* __restrict__ c3,
                                                    const float* __restrict__ vr,
                                                    const float* __restrict__ stats,
                                                    float* __restrict__ refpt,
                                                    float* __restrict__ corr_all) {
  int i = blockIdx.x * 256 + threadIdx.x;
  if (i >= MT) return;
  int b = i / NTOT, n = i % NTOT;
  int l = (n < 8464) ? 0 : (n < 10580) ? 1 : (n < 11109) ? 2 : 3;
  const int LS[4] = {92, 46, 23, 12};
  const int LSTART[4] = {0, 8464, 10580, 11109};
  const int LHW[4] = {8464, 2116, 529, 144};
  int S = LS[l], start = LSTART[l], HW = LHW[l];
  int local = n - start;
  int x = local % S, y = local / S;
  float vrx = vr[(b * 4 + l) * 2 + 0], vry = vr[(b * 4 + l) * 2 + 1];
  float rx = ((float)x + 0.5f) / (vrx * (float)S);
  float ry = ((float)y + 0.5f) / (vry * (float)S);
  const float* cp = (l == 0) ? c0 : (l == 1) ? c1 : (l == 2) ? c2 : c3;
  float c = cp[(size_t)b * HW + local];
  const float* st = stats + (size_t)(b * 4 + l) * 4;
  float mx = st[0], den = st[1], cxs = st[2], cys = st[3];
  float sm = 0.f, cenx = 0.f, ceny = 0.f;
  if (den > 0.f) {
    if (c >= 0.5f) sm = expf(c - mx) / fmaxf(den, 1e-30f);
    cenx = cxs / den; ceny = cys / den;
  }
  float dx = fminf(fmaxf(cenx - rx, -0.5f), 0.5f) * sm;
  float dy = fminf(fmaxf(ceny - ry, -0.5f), 0.5f) * sm;
  refpt[2 * i] = rx + dx;
  refpt[2 * i + 1] = ry + dy;
  corr_all[i] = c;
}

// ---------------- bf16 MFMA GEMM: C[M,N] = A[M,K] * Bt[N,K]^T ----------------
// EPI: 0 = f32 out + bias
//      1 = f32 out + bias + corr[row]*cvec[col]
//      2 = f32 out + bias + resid[row*N+col]
//      3 = bf16 out = bf16(relu(acc + bias))
//      4 = bf16 out = bf16(acc + bias)
template <int EPI>
__global__ __launch_bounds__(256) void gemm_bf16(const unsigned short* __restrict__ A,
                                                 const unsigned short* __restrict__ Bt,
                                                 const float* __restrict__ bias,
                                                 const float* __restrict__ cvec,
                                                 const float* __restrict__ corr,
                                                 const float* __restrict__ resid,
                                                 void* __restrict__ out,
                                                 int K, int N) {
  const int tid = threadIdx.x;
  const int wid = tid >> 6, lane = tid & 63;
  const int row0 = blockIdx.x * 64;
  const int col0 = blockIdx.y * 128;
  const int wm = wid >> 1, wn = wid & 1;
  const int l15 = lane & 15, lk = (lane >> 4) * 8;

  __shared__ __align__(16) unsigned short Als[64 * 40];
  __shared__ __align__(16) unsigned short Bls[128 * 40];

  f32x4 acc[2][4];
  const f32x4 zero = {0.f, 0.f, 0.f, 0.f};
#pragma unroll
  for (int a = 0; a < 2; ++a)
#pragma unroll
    for (int c = 0; c < 4; ++c) acc[a][c] = zero;

  const int srow = tid >> 2, sseg = tid & 3;
  for (int k0 = 0; k0 < K; k0 += 32) {
    __syncthreads();
    {
      int grow = row0 + srow;
      uint4 v = make_uint4(0, 0, 0, 0);
      if (grow < MT) v = *(const uint4*)(A + (size_t)grow * K + k0 + sseg * 8);
      *(uint4*)(&Als[srow * 40 + sseg * 8]) = v;
    }
#pragma unroll
    for (int it = 0; it < 2; ++it) {
      int r = srow + it * 64;
      uint4 v = *(const uint4*)(Bt + (size_t)(col0 + r) * K + k0 + sseg * 8);
      *(uint4*)(&Bls[r * 40 + sseg * 8]) = v;
    }
    __syncthreads();
    bf16x8 av[2], bv[4];
#pragma unroll
    for (int fm = 0; fm < 2; ++fm)
      av[fm] = *(const bf16x8*)(&Als[(wm * 32 + fm * 16 + l15) * 40 + lk]);
#pragma unroll
    for (int fn = 0; fn < 4; ++fn)
      bv[fn] = *(const bf16x8*)(&Bls[(wn * 64 + fn * 16 + l15) * 40 + lk]);
#pragma unroll
    for (int fm = 0; fm < 2; ++fm)
#pragma unroll
      for (int fn = 0; fn < 4; ++fn)
        acc[fm][fn] = __builtin_amdgcn_mfma_f32_16x16x32_bf16(av[fm], bv[fn], acc[fm][fn], 0, 0, 0);
  }

#pragma unroll
  for (int fm = 0; fm < 2; ++fm) {
#pragma unroll
    for (int fn = 0; fn < 4; ++fn) {
      int gcol = col0 + wn * 64 + fn * 16 + l15;
      float bcol = bias[gcol];
#pragma unroll
      for (int r = 0; r < 4; ++r) {
        int grow = row0 + wm * 32 + fm * 16 + (lane >> 4) * 4 + r;
        if (grow < MT) {
          float v = acc[fm][fn][r] + bcol;
          if constexpr (EPI == 1) v += corr[grow] * cvec[gcol];
          if constexpr (EPI == 2) v += resid[(size_t)grow * N + gcol];
          if constexpr (EPI == 3) {
            ((unsigned short*)out)[(size_t)grow * N + gcol] = f2bf(fmaxf(v, 0.f));
          } else if constexpr (EPI == 4) {
            ((unsigned short*)out)[(size_t)grow * N + gcol] = f2bf(v);
          } else {
            ((float*)out)[(size_t)grow * N + gcol] = v;
          }
        }
      }
    }
  }
}

// ---------------- softmax over groups of 16 (attn weights) ----------------
__global__ __launch_bounds__(256) void softmax16(float* __restrict__ a) {
  int idx = blockIdx.x * 256 + threadIdx.x;
  if (idx >= MT * 8) return;
  float* p = a + (size_t)idx * 16;
  float4 v0 = ((float4*)p)[0], v1 = ((float4*)p)[1], v2 = ((float4*)p)[2], v3 = ((float4*)p)[3];
  float m = fmaxf(fmaxf(fmaxf(v0.x, v0.y), fmaxf(v0.z, v0.w)),
                  fmaxf(fmaxf(fmaxf(v1.x, v1.y), fmaxf(v1.z, v1.w)),
                        fmaxf(fmaxf(fmaxf(v2.x, v2.y), fmaxf(v2.z, v2.w)),
                              fmaxf(fmaxf(v3.x, v3.y), fmaxf(v3.z, v3.w)))));
  v0.x = expf(v0.x - m); v0.y = expf(v0.y - m); v0.z = expf(v0.z - m); v0.w = expf(v0.w - m);
  v1.x = expf(v1.x - m); v1.y = expf(v1.y - m); v1.z = expf(v1.z - m); v1.w = expf(v1.w - m);
  v2.x = expf(v2.x - m); v2.y = expf(v2.y - m); v2.z = expf(v2.z - m); v2.w = expf(v2.w - m);
  v3.x = expf(v3.x - m); v3.y = expf(v3.y - m); v3.z = expf(v3.z - m); v3.w = expf(v3.w - m);
  float s = v0.x + v0.y + v0.z + v0.w + v1.x + v1.y + v1.z + v1.w +
            v2.x + v2.y + v2.z + v2.w + v3.x + v3.y + v3.z + v3.w;
  float inv = 1.f / s;
  v0.x *= inv; v0.y *= inv; v0.z *= inv; v0.w *= inv;
  v1.x *= inv; v1.y *= inv; v1.z *= inv; v1.w *= inv;
  v2.x *= inv; v2.y *= inv; v2.z *= inv; v2.w *= inv;
  v3.x *= inv; v3.y *= inv; v3.z *= inv; v3.w *= inv;
  ((float4*)p)[0] = v0; ((float4*)p)[1] = v1; ((float4*)p)[2] = v2; ((float4*)p)[3] = v3;
}

// ---------------- deformable sampling (two-phase, bf16 value) ----------------
// block = 256 threads = 2 rows; per row: phase1 128 pts, phase2 8 heads x 16 chpairs
__global__ __launch_bounds__(256) void sampler2_kernel(const unsigned short* __restrict__ value,
                                                       const float* __restrict__ offs,
                                                       const float* __restrict__ attw,
                                                       const float* __restrict__ refpt,
                                                       const float* __restrict__ vr,
                                                       unsigned short* __restrict__ outs) {
  const int LS[4] = {92, 46, 23, 12};
  const int LSTART[4] = {0, 8464, 10580, 11109};
  const int tid = threadIdx.x;
  const int rsel = tid >> 7;
  const int r = blockIdx.x * 2 + rsel;

  __shared__ __align__(16) int4 s_addr[2][128];
  __shared__ __align__(16) float4 s_w[2][128];

  // ---- phase 1: one thread per (h,l,p) point ----
  {
    int pt = tid & 127;
    int l = (pt >> 2) & 3;
    int h = pt >> 4;
    int b = r / NTOT;
    float ox = offs[(size_t)r * 256 + pt * 2];
    float oy = offs[(size_t)r * 256 + pt * 2 + 1];
    float aw = attw[(size_t)r * 128 + pt];
    float rx = refpt[2 * r], ry = refpt[2 * r + 1];
    float vrx = vr[(b * 4 + l) * 2 + 0], vry = vr[(b * 4 + l) * 2 + 1];
    int S = LS[l];
    float fS = (float)S;
    float xf = rx * vrx * fS + ox - 0.5f;
    float yf = ry * vry * fS + oy - 0.5f;
    float x0f = floorf(xf), y0f = floorf(yf);
    float wx = xf - x0f, wy = yf - y0f;
    int x0 = (int)x0f, y0 = (int)y0f;
    int x1 = x0 + 1, y1 = y0 + 1;
    float vx0 = ((unsigned)x0 < (unsigned)S) ? 1.f : 0.f;
    float vx1 = ((unsigned)x1 < (unsigned)S) ? 1.f : 0.f;
    float vy0 = ((unsigned)y0 < (unsigned)S) ? 1.f : 0.f;
    float vy1 = ((unsigned)y1 < (unsigned)S) ? 1.f : 0.f;
    int cx0 = min(max(x0, 0), S - 1), cx1 = min(max(x1, 0), S - 1);
    int cy0 = min(max(y0, 0), S - 1), cy1 = min(max(y1, 0), S - 1);
    // byte base of (b, token, head) in bf16 value: token stride 512B, head stride 64B
    int base = (b * NTOT + LSTART[l]) * 512 + h * 64;
    int4 a;
    a.x = base + (cy0 * S + cx0) * 512;
    a.y = base + (cy0 * S + cx1) * 512;
    a.z = base + (cy1 * S + cx0) * 512;
    a.w = base + (cy1 * S + cx1) * 512;
    float iwx = 1.f - wx, iwy = 1.f - wy;
    float4 w;
    w.x = aw * iwx * iwy * vx0 * vy0;
    w.y = aw * wx * iwy * vx1 * vy0;
    w.z = aw * iwx * wy * vx0 * vy1;
    w.w = aw * wx * wy * vx1 * vy1;
    s_addr[rsel][pt] = a;
    s_w[rsel][pt] = w;
  }
  __syncthreads();

  // ---- phase 2: (h, chpair) accumulate over 16 points ----
  const int h = (tid >> 4) & 7, cp = tid & 15;
  const char* vb = (const char*)value;
  const int cpo = cp * 4;
  float a0 = 0.f, a1 = 0.f;
#pragma unroll 4
  for (int i = 0; i < 16; ++i) {
    int4 a = s_addr[rsel][h * 16 + i];
    float4 w = s_w[rsel][h * 16 + i];
    unsigned u00 = *(const unsigned*)(vb + (size_t)(unsigned)(a.x + cpo));
    unsigned u01 = *(const unsigned*)(vb + (size_t)(unsigned)(a.y + cpo));
    unsigned u10 = *(const unsigned*)(vb + (size_t)(unsigned)(a.z + cpo));
    unsigned u11 = *(const unsigned*)(vb + (size_t)(unsigned)(a.w + cpo));
    float f00l = __uint_as_float(u00 << 16), f00h = __uint_as_float(u00 & 0xFFFF0000u);
    float f01l = __uint_as_float(u01 << 16), f01h = __uint_as_float(u01 & 0xFFFF0000u);
    float f10l = __uint_as_float(u10 << 16), f10h = __uint_as_float(u10 & 0xFFFF0000u);
    float f11l = __uint_as_float(u11 << 16), f11h = __uint_as_float(u11 & 0xFFFF0000u);
    a0 += w.x * f00l + w.y * f01l + w.z * f10l + w.w * f11l;
    a1 += w.x * f00h + w.y * f01h + w.z * f10h + w.w * f11h;
  }
  unsigned packed = (unsigned)f2bf(a0) | ((unsigned)f2bf(a1) << 16);
  ((unsigned*)outs)[(size_t)r * 128 + h * 16 + cp] = packed;
}

// ---------------- layernorm (256 cols, 1 wave per row) ----------------
__global__ __launch_bounds__(256) void ln_kernel(const float* __restrict__ in,
                                                 const float* __restrict__ g,
                                                 const float* __restrict__ b,
                                                 float* __restrict__ outf,
                                                 ushort4* __restrict__ outbf) {
  int row = blockIdx.x * 4 + (threadIdx.x >> 6);
  int lane = threadIdx.x & 63;
  if (row >= MT) return;
  const float4* p = (const float4*)(in + (size_t)row * 256);
  float4 v = p[lane];
  float s = v.x + v.y + v.z + v.w;
  for (int o = 32; o; o >>= 1) s += __shfl_xor(s, o);
  float mean = s * (1.f / 256.f);
  float dx = v.x - mean, dy = v.y - mean, dz = v.z - mean, dw = v.w - mean;
  float q = dx * dx + dy * dy + dz * dz + dw * dw;
  for (int o = 32; o; o >>= 1) q += __shfl_xor(q, o);
  float rstd = rsqrtf(q * (1.f / 256.f) + 1e-5f);
  float4 gv = ((const float4*)g)[lane];
  float4 bv = ((const float4*)b)[lane];
  float4 o;
  o.x = dx * rstd * gv.x + bv.x;
  o.y = dy * rstd * gv.y + bv.y;
  o.z = dz * rstd * gv.z + bv.z;
  o.w = dw * rstd * gv.w + bv.w;
  ((float4*)(outf + (size_t)row * 256))[lane] = o;
  if (outbf) outbf[(size_t)row * 64 + lane] = make_ushort4(f2bf(o.x), f2bf(o.y), f2bf(o.z), f2bf(o.w));
}

// ---------------- launch ----------------
extern "C" void kernel_launch(void* const* d_in, const int* in_sizes, int n_in,
                              void* d_out, int out_size, void* d_ws, size_t ws_size,
                              hipStream_t stream) {
  (void)in_sizes; (void)n_in; (void)out_size; (void)ws_size;
  const float* src = (const float*)d_in[0];
  const float* pos = (const float*)d_in[1];
  const float* c0 = (const float*)d_in[2];
  const float* c1 = (const float*)d_in[3];
  const float* c2 = (const float*)d_in[4];
  const float* c3 = (const float*)d_in[5];
  const float* vr = (const float*)d_in[6];
  const float* W_off = (const float*)d_in[8];
  const float* b_off = (const float*)d_in[9];
  const float* W_attn = (const float*)d_in[10];
  const float* b_attn = (const float*)d_in[11];
  const float* W_val = (const float*)d_in[12];
  const float* b_val = (const float*)d_in[13];
  const float* W_out = (const float*)d_in[14];
  const float* b_out = (const float*)d_in[15];
  const float* ln1g = (const float*)d_in[16];
  const float* ln1b = (const float*)d_in[17];
  const float* W1 = (const float*)d_in[18];
  const float* b1 = (const float*)d_in[19];
  const float* W2 = (const float*)d_in[20];
  const float* b2 = (const float*)d_in[21];
  const float* ln2g = (const float*)d_in[22];
  const float* ln2b = (const float*)d_in[23];

  char* ws = (char*)d_ws;
  // slot S1 (46MB): value_bf16 (23MB) -> t -> x -> u (f32 46MB)
  unsigned short* value_bf = (unsigned short*)(ws + 0);
  float* tbuf = (float*)(ws + 0);
  float* xbuf = tbuf;
  float* ubuf = tbuf;
  // slot S2 (46MB): offs; later x_bf16 in front half
  float* offs = (float*)(ws + 46092288);
  unsigned short* x_bf16 = (unsigned short*)(ws + 46092288);
  // slot S4 (23MB): src_bf16 -> out_s
  unsigned short* src_bf16 = (unsigned short*)(ws + 92184576);
  unsigned short* out_s = src_bf16;
  // region C (92MB): qa (front 23MB) + logits (next 23MB); later h spans all
  unsigned short* qa = (unsigned short*)(ws + 115230720);
  float* logits = (float*)(ws + 138276864);
  unsigned short* hbuf = (unsigned short*)(ws + 115230720);
  // small region
  unsigned short* Wt_val = (unsigned short*)(ws + 207415296);
  unsigned short* Wt_off = (unsigned short*)(ws + 207546368);
  unsigned short* Wt_attn = (unsigned short*)(ws + 207677440);
  unsigned short* Wt_out = (unsigned short*)(ws + 207742976);
  unsigned short* Wt1 = (unsigned short*)(ws + 207874048);
  unsigned short* Wt2 = (unsigned short*)(ws + 208398336);
  float* c_off = (float*)(ws + 208922624);
  float* c_attn = (float*)(ws + 208923648);
  float* refpt = (float*)(ws + 208924160);
  float* corr_all = (float*)(ws + 209284256);
  float* stats = (float*)(ws + 209464304);

  // weight prep
  wt_transpose<<<256, 256, 0, stream>>>(W_val, Wt_val, 256, 256);
  wt_transpose<<<256, 256, 0, stream>>>(W_off, Wt_off, 256, 256);
  wt_transpose<<<128, 256, 0, stream>>>(W_attn, Wt_attn, 256, 128);
  wt_transpose<<<256, 256, 0, stream>>>(W_out, Wt_out, 256, 256);
  wt_transpose<<<1024, 256, 0, stream>>>(W1, Wt1, 256, 1024);
  wt_transpose<<<1024, 256, 0, stream>>>(W2, Wt2, 1024, 256);
  cvec_kernel<<<2, 256, 0, stream>>>(W_off, W_attn, c_off, c_attn);

  // activations
  cvt_kernel<<<11253, 256, 0, stream>>>((const float4*)src, (const float4*)pos,
                                        (ushort4*)src_bf16, (ushort4*)qa);
  // reference points
  stats_kernel<<<16, 256, 0, stream>>>(c0, c1, c2, c3, vr, stats);
  refpt_kernel<<<176, 256, 0, stream>>>(c0, c1, c2, c3, vr, stats, refpt, corr_all);

  dim3 blk(256);
  // value = bf16(src @ W_val + b_val)
  gemm_bf16<4><<<dim3(704, 2), blk, 0, stream>>>(src_bf16, Wt_val, b_val, nullptr, nullptr, nullptr, value_bf, 256, 256);
  // offsets = qa @ W_off + corr*c_off + b_off
  gemm_bf16<1><<<dim3(704, 2), blk, 0, stream>>>(qa, Wt_off, b_off, c_off, corr_all, nullptr, offs, 256, 256);
  // attn logits
  gemm_bf16<1><<<dim3(704, 1), blk, 0, stream>>>(qa, Wt_attn, b_attn, c_attn, corr_all, nullptr, logits, 256, 128);
  softmax16<<<1407, 256, 0, stream>>>(logits);
  // deformable sampling -> out_s (bf16)
  sampler2_kernel<<<MT / 2, 256, 0, stream>>>(value_bf, offs, logits, refpt, vr, out_s);
  // out proj + residual: t = out_s @ W_out + b_out + src
  gemm_bf16<2><<<dim3(704, 2), blk, 0, stream>>>(out_s, Wt_out, b_out, nullptr, nullptr, src, tbuf, 256, 256);
  // LN1: x (f32, in-place) + x_bf16
  ln_kernel<<<11253, 256, 0, stream>>>(tbuf, ln1g, ln1b, xbuf, (ushort4*)x_bf16);
  // FFN1: h = bf16(relu(x @ W1 + b1))
  gemm_bf16<3><<<dim3(704, 8), blk, 0, stream>>>(x_bf16, Wt1, b1, nullptr, nullptr, nullptr, hbuf, 256, 1024);
  // FFN2: u = h @ W2 + b2 + x  (in-place into S1)
  gemm_bf16<2><<<dim3(704, 2), blk, 0, stream>>>(hbuf, Wt2, b2, nullptr, nullptr, xbuf, ubuf, 1024, 256);
  // LN2 -> d_out
  ln_kernel<<<11253, 256, 0, stream>>>(ubuf, ln2g, ln2b, (float*)d_out, nullptr);
}

// Round 5
// 375.190 us; speedup vs baseline: 1.6249x; 1.0409x over previous
//
#include <hip/hip_runtime.h>

#define MT 45012
#define NTOT 11253
#define BB 4

typedef __attribute__((ext_vector_type(8))) __bf16 bf16x8;
typedef __attribute__((ext_vector_type(4))) float f32x4;

__device__ __forceinline__ unsigned short f2bf(float f) {
  unsigned u = __float_as_uint(f);
  u += 0x7FFFu + ((u >> 16) & 1u);
  return (unsigned short)(u >> 16);
}

__device__ __forceinline__ void gld16(const unsigned short* g, unsigned short* l) {
  __builtin_amdgcn_global_load_lds((const __attribute__((address_space(1))) unsigned int*)g,
                                   (__attribute__((address_space(3))) unsigned int*)l, 16, 0, 0);
}

// ---------------- unified weight prep: 6 transposes + tail vectors ----------------
__global__ __launch_bounds__(256) void prep_kernel(const float* __restrict__ Wv, const float* __restrict__ Wo,
                                                   const float* __restrict__ Wa, const float* __restrict__ Wu,
                                                   const float* __restrict__ W1, const float* __restrict__ W2,
                                                   unsigned short* __restrict__ Tv, unsigned short* __restrict__ To,
                                                   unsigned short* __restrict__ Ta, unsigned short* __restrict__ Tu,
                                                   unsigned short* __restrict__ T1, unsigned short* __restrict__ T2,
                                                   float* __restrict__ c_off, float* __restrict__ c_attn) {
  int bid = blockIdx.x, t = threadIdx.x;
  const float* W; unsigned short* T; int K, N, base;
  if (bid < 256)       { W = Wv; T = Tv; K = 256;  N = 256;  base = 0; }
  else if (bid < 512)  { W = Wo; T = To; K = 256;  N = 256;  base = 256; }
  else if (bid < 640)  { W = Wa; T = Ta; K = 256;  N = 128;  base = 512; }
  else if (bid < 896)  { W = Wu; T = Tu; K = 256;  N = 256;  base = 640; }
  else if (bid < 1920) { W = W1; T = T1; K = 256;  N = 1024; base = 896; }
  else if (bid < 2944) { W = W2; T = T2; K = 1024; N = 256;  base = 1920; }
  else {
    int i = (bid - 2944) * 256 + t;
    if (i < 256) c_off[i] = Wo[256 * 256 + i];
    else if (i < 384) c_attn[i - 256] = Wa[256 * 128 + (i - 256)];
    return;
  }
  int i = (bid - base) * 256 + t;
  int n = i / K, k = i % K;
  T[i] = f2bf(W[(size_t)k * N + n]);
}

// ---------------- activation convert: src_bf16, qa = bf16(src+pos) ----------------
__global__ __launch_bounds__(256) void cvt_kernel(const float4* __restrict__ src4,
                                                  const float4* __restrict__ pos4,
                                                  ushort4* __restrict__ sb,
                                                  ushort4* __restrict__ qb) {
  int i = blockIdx.x * 256 + threadIdx.x;
  if (i >= MT * 64) return;
  float4 s = src4[i], p = pos4[i];
  sb[i] = make_ushort4(f2bf(s.x), f2bf(s.y), f2bf(s.z), f2bf(s.w));
  qb[i] = make_ushort4(f2bf(s.x + p.x), f2bf(s.y + p.y), f2bf(s.z + p.z), f2bf(s.w + p.w));
}

// ---------------- per (b,level) corr-softmax stats ----------------
__global__ __launch_bounds__(256) void stats_kernel(const float* __restrict__ c0,
                                                    const float* __restrict__ c1,
                                                    const float* __restrict__ c2,
                                                    const float* __restrict__ c3,
                                                    const float* __restrict__ vr,
                                                    float* __restrict__ stats) {
  const int LS[4] = {92, 46, 23, 12};
  const int LHW[4] = {8464, 2116, 529, 144};
  int b = blockIdx.x >> 2, l = blockIdx.x & 3;
  const float* cp = (l == 0) ? c0 : (l == 1) ? c1 : (l == 2) ? c2 : c3;
  int S = LS[l], HW = LHW[l];
  float vrx = vr[(b * 4 + l) * 2 + 0], vry = vr[(b * 4 + l) * 2 + 1];
  int tid = threadIdx.x;
  __shared__ float red[4];

  float mx = -INFINITY;
  for (int i = tid; i < HW; i += 256) {
    float c = cp[(size_t)b * HW + i];
    if (c >= 0.5f) mx = fmaxf(mx, c);
  }
  for (int o = 32; o; o >>= 1) mx = fmaxf(mx, __shfl_xor(mx, o));
  if ((tid & 63) == 0) red[tid >> 6] = mx;
  __syncthreads();
  mx = fmaxf(fmaxf(red[0], red[1]), fmaxf(red[2], red[3]));
  float mx_eff = isinf(mx) ? 0.f : mx;
  __syncthreads();

  float den = 0.f, cx = 0.f, cy = 0.f;
  float invW = 1.f / (vrx * (float)S), invH = 1.f / (vry * (float)S);
  for (int i = tid; i < HW; i += 256) {
    float c = cp[(size_t)b * HW + i];
    if (c >= 0.5f) {
      float e = expf(c - mx_eff);
      int x = i % S, y = i / S;
      den += e;
      cx += e * ((float)x + 0.5f) * invW;
      cy += e * ((float)y + 0.5f) * invH;
    }
  }
  float vals[3] = {den, cx, cy};
  for (int j = 0; j < 3; ++j) {
    float v = vals[j];
    for (int o = 32; o; o >>= 1) v += __shfl_xor(v, o);
    if ((tid & 63) == 0) red[tid >> 6] = v;
    __syncthreads();
    v = red[0] + red[1] + red[2] + red[3];
    vals[j] = v;
    __syncthreads();
  }
  if (tid == 0) {
    float* s = stats + (size_t)(b * 4 + l) * 4;
    s[0] = mx_eff; s[1] = vals[0]; s[2] = vals[1]; s[3] = vals[2];
  }
}

// ---------------- reference points + corr_all ----------------
__global__ __launch_bounds__(256) void refpt_kernel(const float* __restrict__ c0,
                                                    const float* __restrict__ c1,
                                                    const float* __restrict__ c2,
                                                    const float* __restrict__ c3,
                                                    const float* __restrict__ vr,
                                                    const float* __restrict__ stats,
                                                    float* __restrict__ refpt,
                                                    float* __restrict__ corr_all) {
  int i = blockIdx.x * 256 + threadIdx.x;
  if (i >= MT) return;
  int b = i / NTOT, n = i % NTOT;
  int l = (n < 8464) ? 0 : (n < 10580) ? 1 : (n < 11109) ? 2 : 3;
  const int LS[4] = {92, 46, 23, 12};
  const int LSTART[4] = {0, 8464, 10580, 11109};
  const int LHW[4] = {8464, 2116, 529, 144};
  int S = LS[l], start = LSTART[l], HW = LHW[l];
  int local = n - start;
  int x = local % S, y = local / S;
  float vrx = vr[(b * 4 + l) * 2 + 0], vry = vr[(b * 4 + l) * 2 + 1];
  float rx = ((float)x + 0.5f) / (vrx * (float)S);
  float ry = ((float)y + 0.5f) / (vry * (float)S);
  const float* cp = (l == 0) ? c0 : (l == 1) ? c1 : (l == 2) ? c2 : c3;
  float c = cp[(size_t)b * HW + local];
  const float* st = stats + (size_t)(b * 4 + l) * 4;
  float mx = st[0], den = st[1], cxs = st[2], cys = st[3];
  float sm = 0.f, cenx = 0.f, ceny = 0.f;
  if (den > 0.f) {
    if (c >= 0.5f) sm = expf(c - mx) / fmaxf(den, 1e-30f);
    cenx = cxs / den; ceny = cys / den;
  }
  float dx = fminf(fmaxf(cenx - rx, -0.5f), 0.5f) * sm;
  float dy = fminf(fmaxf(ceny - ry, -0.5f), 0.5f) * sm;
  refpt[2 * i] = rx + dx;
  refpt[2 * i + 1] = ry + dy;
  corr_all[i] = c;
}

// ---------------- bf16 MFMA GEMM, m97 structure: 128x128 tile, BK=32, gload_lds ----------------
// EPI: 0 = f32 out + bias
//      1 = f32 out + bias + corr[row]*cvec[col]
//      2 = f32 out + bias + resid[row*N+col]
//      3 = bf16 out = bf16(relu(acc + bias))
//      4 = bf16 out = bf16(acc + bias)
template <int EPI>
__global__ __launch_bounds__(256) void gemm128(const unsigned short* __restrict__ A,
                                               const unsigned short* __restrict__ Bt,
                                               const float* __restrict__ bias,
                                               const float* __restrict__ cvec,
                                               const float* __restrict__ corr,
                                               const float* __restrict__ resid,
                                               void* __restrict__ out,
                                               int K, int N) {
  const int tid = threadIdx.x;
  const int wid = tid >> 6, lane = tid & 63;
  const int row0 = blockIdx.x * 128;
  const int col0 = blockIdx.y * 128;
  const int wm = wid >> 1, wn = wid & 1;
  const int l15 = lane & 15;
  const int hi = lane >> 4;  // 0..3

  __shared__ __align__(16) unsigned short Als[128 * 32];
  __shared__ __align__(16) unsigned short Bls[128 * 32];

  f32x4 acc[4][4];
  const f32x4 zero = {0.f, 0.f, 0.f, 0.f};
#pragma unroll
  for (int a = 0; a < 4; ++a)
#pragma unroll
    for (int c = 0; c < 4; ++c) acc[a][c] = zero;

  // staging: chunk i covers LDS bytes [i*16, i*16+16) = tile row i>>2, 16B-chunk i&3
  const int i0 = tid, i1 = 256 + tid;
  int ar0 = row0 + (i0 >> 2); if (ar0 > MT - 1) ar0 = MT - 1;
  int ar1 = row0 + (i1 >> 2); if (ar1 > MT - 1) ar1 = MT - 1;
  const unsigned short* ga0 = A + (size_t)ar0 * K + (i0 & 3) * 8;
  const unsigned short* ga1 = A + (size_t)ar1 * K + (i1 & 3) * 8;
  const unsigned short* gb0 = Bt + (size_t)(col0 + (i0 >> 2)) * K + (i0 & 3) * 8;
  const unsigned short* gb1 = Bt + (size_t)(col0 + (i1 >> 2)) * K + (i1 & 3) * 8;
  unsigned short* la0 = Als + i0 * 8;
  unsigned short* la1 = Als + i1 * 8;
  unsigned short* lb0 = Bls + i0 * 8;
  unsigned short* lb1 = Bls + i1 * 8;

  for (int k0 = 0; k0 < K; k0 += 32) {
    __syncthreads();  // prev iteration's LDS reads done
    gld16(ga0 + k0, la0);
    gld16(ga1 + k0, la1);
    gld16(gb0 + k0, lb0);
    gld16(gb1 + k0, lb1);
    __syncthreads();  // vmcnt(0) drain -> LDS tile complete
    bf16x8 av[4], bv[4];
#pragma unroll
    for (int f = 0; f < 4; ++f) {
      av[f] = *(const bf16x8*)(Als + (wm * 64 + f * 16 + l15) * 32 + hi * 8);
      bv[f] = *(const bf16x8*)(Bls + (wn * 64 + f * 16 + l15) * 32 + hi * 8);
    }
#pragma unroll
    for (int fm = 0; fm < 4; ++fm)
#pragma unroll
      for (int fn = 0; fn < 4; ++fn)
        acc[fm][fn] = __builtin_amdgcn_mfma_f32_16x16x32_bf16(av[fm], bv[fn], acc[fm][fn], 0, 0, 0);
  }

#pragma unroll
  for (int fm = 0; fm < 4; ++fm) {
#pragma unroll
    for (int fn = 0; fn < 4; ++fn) {
      int gcol = col0 + wn * 64 + fn * 16 + l15;
      float bcol = bias[gcol];
      float cv = 0.f;
      if constexpr (EPI == 1) cv = cvec[gcol];
#pragma unroll
      for (int r = 0; r < 4; ++r) {
        int grow = row0 + wm * 64 + fm * 16 + hi * 4 + r;
        if (grow < MT) {
          float v = acc[fm][fn][r] + bcol;
          if constexpr (EPI == 1) v += corr[grow] * cv;
          if constexpr (EPI == 2) v += resid[(size_t)grow * N + gcol];
          if constexpr (EPI == 3) {
            ((unsigned short*)out)[(size_t)grow * N + gcol] = f2bf(fmaxf(v, 0.f));
          } else if constexpr (EPI == 4) {
            ((unsigned short*)out)[(size_t)grow * N + gcol] = f2bf(v);
          } else {
            ((float*)out)[(size_t)grow * N + gcol] = v;
          }
        }
      }
    }
  }
}

// ---------------- deformable sampling (two-phase, bf16 value, fused softmax) ----------------
// block = 256 threads = 2 rows; per row: phase1 128 pts (+16-group softmax), phase2 8 heads x 16 chpairs
__global__ __launch_bounds__(256) void sampler2_kernel(const unsigned short* __restrict__ value,
                                                       const float* __restrict__ offs,
                                                       const float* __restrict__ logits,
                                                       const float* __restrict__ refpt,
                                                       const float* __restrict__ vr,
                                                       unsigned short* __restrict__ outs) {
  const int LS[4] = {92, 46, 23, 12};
  const int LSTART[4] = {0, 8464, 10580, 11109};
  const int tid = threadIdx.x;
  const int rsel = tid >> 7;
  const int r = blockIdx.x * 2 + rsel;

  __shared__ __align__(16) int4 s_addr[2][8][17];
  __shared__ __align__(16) float4 s_w[2][8][17];

  // ---- phase 1: one thread per (h,l,p) point ----
  {
    int pt = tid & 127;
    int l = (pt >> 2) & 3;
    int h = pt >> 4;
    int b = r / NTOT;
    float ox = offs[(size_t)r * 256 + pt * 2];
    float oy = offs[(size_t)r * 256 + pt * 2 + 1];
    float lg = logits[(size_t)r * 128 + pt];
    // softmax over the 16-point group (lanes pt&~15 .. pt|15, within-wave)
    float m = lg;
    for (int o = 1; o < 16; o <<= 1) m = fmaxf(m, __shfl_xor(m, o));
    float e = expf(lg - m);
    float s = e;
    for (int o = 1; o < 16; o <<= 1) s += __shfl_xor(s, o);
    float aw = e / s;

    float rx = refpt[2 * r], ry = refpt[2 * r + 1];
    float vrx = vr[(b * 4 + l) * 2 + 0], vry = vr[(b * 4 + l) * 2 + 1];
    int S = LS[l];
    float fS = (float)S;
    float xf = rx * vrx * fS + ox - 0.5f;
    float yf = ry * vry * fS + oy - 0.5f;
    float x0f = floorf(xf), y0f = floorf(yf);
    float wx = xf - x0f, wy = yf - y0f;
    int x0 = (int)x0f, y0 = (int)y0f;
    int x1 = x0 + 1, y1 = y0 + 1;
    float vx0 = ((unsigned)x0 < (unsigned)S) ? 1.f : 0.f;
    float vx1 = ((unsigned)x1 < (unsigned)S) ? 1.f : 0.f;
    float vy0 = ((unsigned)y0 < (unsigned)S) ? 1.f : 0.f;
    float vy1 = ((unsigned)y1 < (unsigned)S) ? 1.f : 0.f;
    int cx0 = min(max(x0, 0), S - 1), cx1 = min(max(x1, 0), S - 1);
    int cy0 = min(max(y0, 0), S - 1), cy1 = min(max(y1, 0), S - 1);
    // byte base of (b, token, head) in bf16 value: token stride 512B, head stride 64B
    int base = (b * NTOT + LSTART[l]) * 512 + h * 64;
    int4 a;
    a.x = base + (cy0 * S + cx0) * 512;
    a.y = base + (cy0 * S + cx1) * 512;
    a.z = base + (cy1 * S + cx0) * 512;
    a.w = base + (cy1 * S + cx1) * 512;
    float iwx = 1.f - wx, iwy = 1.f - wy;
    float4 w;
    w.x = aw * iwx * iwy * vx0 * vy0;
    w.y = aw * wx * iwy * vx1 * vy0;
    w.z = aw * iwx * wy * vx0 * vy1;
    w.w = aw * wx * wy * vx1 * vy1;
    s_addr[rsel][h][pt & 15] = a;
    s_w[rsel][h][pt & 15] = w;
  }
  __syncthreads();

  // ---- phase 2: (h, chpair) accumulate over 16 points ----
  const int h = (tid >> 4) & 7, cp = tid & 15;
  const char* vb = (const char*)value;
  const int cpo = cp * 4;
  float a0 = 0.f, a1 = 0.f;
#pragma unroll 4
  for (int i = 0; i < 16; ++i) {
    int4 a = s_addr[rsel][h][i];
    float4 w = s_w[rsel][h][i];
    unsigned u00 = *(const unsigned*)(vb + (size_t)(unsigned)(a.x + cpo));
    unsigned u01 = *(const unsigned*)(vb + (size_t)(unsigned)(a.y + cpo));
    unsigned u10 = *(const unsigned*)(vb + (size_t)(unsigned)(a.z + cpo));
    unsigned u11 = *(const unsigned*)(vb + (size_t)(unsigned)(a.w + cpo));
    float f00l = __uint_as_float(u00 << 16), f00h = __uint_as_float(u00 & 0xFFFF0000u);
    float f01l = __uint_as_float(u01 << 16), f01h = __uint_as_float(u01 & 0xFFFF0000u);
    float f10l = __uint_as_float(u10 << 16), f10h = __uint_as_float(u10 & 0xFFFF0000u);
    float f11l = __uint_as_float(u11 << 16), f11h = __uint_as_float(u11 & 0xFFFF0000u);
    a0 += w.x * f00l + w.y * f01l + w.z * f10l + w.w * f11l;
    a1 += w.x * f00h + w.y * f01h + w.z * f10h + w.w * f11h;
  }
  unsigned packed = (unsigned)f2bf(a0) | ((unsigned)f2bf(a1) << 16);
  ((unsigned*)outs)[(size_t)r * 128 + h * 16 + cp] = packed;
}

// ---------------- layernorm (256 cols, 1 wave per row) ----------------
__global__ __launch_bounds__(256) void ln_kernel(const float* __restrict__ in,
                                                 const float* __restrict__ g,
                                                 const float* __restrict__ b,
                                                 float* __restrict__ outf,
                                                 ushort4* __restrict__ outbf) {
  int row = blockIdx.x * 4 + (threadIdx.x >> 6);
  int lane = threadIdx.x & 63;
  if (row >= MT) return;
  const float4* p = (const float4*)(in + (size_t)row * 256);
  float4 v = p[lane];
  float s = v.x + v.y + v.z + v.w;
  for (int o = 32; o; o >>= 1) s += __shfl_xor(s, o);
  float mean = s * (1.f / 256.f);
  float dx = v.x - mean, dy = v.y - mean, dz = v.z - mean, dw = v.w - mean;
  float q = dx * dx + dy * dy + dz * dz + dw * dw;
  for (int o = 32; o; o >>= 1) q += __shfl_xor(q, o);
  float rstd = rsqrtf(q * (1.f / 256.f) + 1e-5f);
  float4 gv = ((const float4*)g)[lane];
  float4 bv = ((const float4*)b)[lane];
  float4 o;
  o.x = dx * rstd * gv.x + bv.x;
  o.y = dy * rstd * gv.y + bv.y;
  o.z = dz * rstd * gv.z + bv.z;
  o.w = dw * rstd * gv.w + bv.w;
  ((float4*)(outf + (size_t)row * 256))[lane] = o;
  if (outbf) outbf[(size_t)row * 64 + lane] = make_ushort4(f2bf(o.x), f2bf(o.y), f2bf(o.z), f2bf(o.w));
}

// ---------------- launch ----------------
extern "C" void kernel_launch(void* const* d_in, const int* in_sizes, int n_in,
                              void* d_out, int out_size, void* d_ws, size_t ws_size,
                              hipStream_t stream) {
  (void)in_sizes; (void)n_in; (void)out_size; (void)ws_size;
  const float* src = (const float*)d_in[0];
  const float* pos = (const float*)d_in[1];
  const float* c0 = (const float*)d_in[2];
  const float* c1 = (const float*)d_in[3];
  const float* c2 = (const float*)d_in[4];
  const float* c3 = (const float*)d_in[5];
  const float* vr = (const float*)d_in[6];
  const float* W_off = (const float*)d_in[8];
  const float* b_off = (const float*)d_in[9];
  const float* W_attn = (const float*)d_in[10];
  const float* b_attn = (const float*)d_in[11];
  const float* W_val = (const float*)d_in[12];
  const float* b_val = (const float*)d_in[13];
  const float* W_out = (const float*)d_in[14];
  const float* b_out = (const float*)d_in[15];
  const float* ln1g = (const float*)d_in[16];
  const float* ln1b = (const float*)d_in[17];
  const float* W1 = (const float*)d_in[18];
  const float* b1 = (const float*)d_in[19];
  const float* W2 = (const float*)d_in[20];
  const float* b2 = (const float*)d_in[21];
  const float* ln2g = (const float*)d_in[22];
  const float* ln2b = (const float*)d_in[23];

  char* ws = (char*)d_ws;
  // slot S1 (46MB): value_bf16 (23MB) -> t -> x -> u (f32 46MB)
  unsigned short* value_bf = (unsigned short*)(ws + 0);
  float* tbuf = (float*)(ws + 0);
  float* xbuf = tbuf;
  float* ubuf = tbuf;
  // slot S2 (46MB): offs; later x_bf16 in front half
  float* offs = (float*)(ws + 46092288);
  unsigned short* x_bf16 = (unsigned short*)(ws + 46092288);
  // slot S4 (23MB): src_bf16 -> out_s
  unsigned short* src_bf16 = (unsigned short*)(ws + 92184576);
  unsigned short* out_s = src_bf16;
  // region C (92MB): qa (front 23MB) + logits (next 23MB); later h spans all
  unsigned short* qa = (unsigned short*)(ws + 115230720);
  float* logits = (float*)(ws + 138276864);
  unsigned short* hbuf = (unsigned short*)(ws + 115230720);
  // small region
  unsigned short* Wt_val = (unsigned short*)(ws + 207415296);
  unsigned short* Wt_off = (unsigned short*)(ws + 207546368);
  unsigned short* Wt_attn = (unsigned short*)(ws + 207677440);
  unsigned short* Wt_out = (unsigned short*)(ws + 207742976);
  unsigned short* Wt1 = (unsigned short*)(ws + 207874048);
  unsigned short* Wt2 = (unsigned short*)(ws + 208398336);
  float* c_off = (float*)(ws + 208922624);
  float* c_attn = (float*)(ws + 208923648);
  float* refpt = (float*)(ws + 208924160);
  float* corr_all = (float*)(ws + 209284256);
  float* stats = (float*)(ws + 209464304);

  // weight prep (single kernel)
  prep_kernel<<<2946, 256, 0, stream>>>(W_val, W_off, W_attn, W_out, W1, W2,
                                        Wt_val, Wt_off, Wt_attn, Wt_out, Wt1, Wt2,
                                        c_off, c_attn);

  // activations
  cvt_kernel<<<11253, 256, 0, stream>>>((const float4*)src, (const float4*)pos,
                                        (ushort4*)src_bf16, (ushort4*)qa);
  // reference points
  stats_kernel<<<16, 256, 0, stream>>>(c0, c1, c2, c3, vr, stats);
  refpt_kernel<<<176, 256, 0, stream>>>(c0, c1, c2, c3, vr, stats, refpt, corr_all);

  dim3 blk(256);
  // value = bf16(src @ W_val + b_val)
  gemm128<4><<<dim3(352, 2), blk, 0, stream>>>(src_bf16, Wt_val, b_val, nullptr, nullptr, nullptr, value_bf, 256, 256);
  // offsets = qa @ W_off + corr*c_off + b_off
  gemm128<1><<<dim3(352, 2), blk, 0, stream>>>(qa, Wt_off, b_off, c_off, corr_all, nullptr, offs, 256, 256);
  // attn logits (softmax fused into sampler)
  gemm128<1><<<dim3(352, 1), blk, 0, stream>>>(qa, Wt_attn, b_attn, c_attn, corr_all, nullptr, logits, 256, 128);
  // deformable sampling -> out_s (bf16)
  sampler2_kernel<<<MT / 2, 256, 0, stream>>>(value_bf, offs, logits, refpt, vr, out_s);
  // out proj + residual: t = out_s @ W_out + b_out + src
  gemm128<2><<<dim3(352, 2), blk, 0, stream>>>(out_s, Wt_out, b_out, nullptr, nullptr, src, tbuf, 256, 256);
  // LN1: x (f32, in-place) + x_bf16
  ln_kernel<<<11253, 256, 0, stream>>>(tbuf, ln1g, ln1b, xbuf, (ushort4*)x_bf16);
  // FFN1: h = bf16(relu(x @ W1 + b1))
  gemm128<3><<<dim3(352, 8), blk, 0, stream>>>(x_bf16, Wt1, b1, nullptr, nullptr, nullptr, hbuf, 256, 1024);
  // FFN2: u = h @ W2 + b2 + x  (in-place into S1)
  gemm128<2><<<dim3(352, 2), blk, 0, stream>>>(hbuf, Wt2, b2, nullptr, nullptr, xbuf, ubuf, 1024, 256);
  // LN2 -> d_out
  ln_kernel<<<11253, 256, 0, stream>>>(ubuf, ln2g, ln2b, (float*)d_out, nullptr);
}